// Round 1
// baseline (698.020 us; speedup 1.0000x reference)
//
#include <hip/hip_runtime.h>
#include <hip/hip_bf16.h>

// LSTM B=256 T=512 H=256 E=6 V=10 C=10. fp32 in/out.
// ROUND 16: barrier-free flag-pipelined steps. r15 convoyed MFMA-then-VALU
// phases behind a per-step __syncthreads (per-active-CU MfmaUtil 44% +
// VALUBusy 56% ~= 100% sequential). Replace the barrier with per-k-slice
// monotonic LDS counters: 4 row-groups (group j = waves 4j..4j+3 owns h rows
// 64j..64j+63); a wave polls wcnt[s] >= 4t right before consuming slice s at
// step t, in rotated order (j+1, j+2, j+3, j) with weights pre-rotated into
// registers (static indexing). Writer: ds_write h bytes -> release LDS
// atomic inc. 2-buffer safety: reaching step-t write implies polls on all
// groups' t-1 writes, which implies all waves finished t-1 reads. Step-0
// group serialization injects skew so one group's elementwise overlaps the
// others' MFMAs (separate pipes). s_setprio(1) around MFMA clusters.
// Structure otherwise r15: 128 blocks x 1024 thr, 2 cols/block, INT8 MFMA
// (mfma_i32_16x16x64_i8), reg-resident per-row-quantized weights, h @127
// double-buffered LDS, bias folded into per-col x-table tblC (80 KB LDS),
// single-rcp c-update (5 exp2 + 2 rcp / elem), constant-index cndmask acc
// select.

typedef __attribute__((ext_vector_type(4))) int   int4v;
typedef __attribute__((ext_vector_type(4))) float float4v;

#define MFMA_I8(a, b, c) __builtin_amdgcn_mfma_i32_16x16x64_i8(a, b, c, 0, 0, 0)

#define K_TANH (-2.8853900817779268f)   // exp2(K_TANH*x) = e^(-2x)
#define K_SIG  (-1.4426950408889634f)   // exp2(K_SIG*x)  = e^(-x)

#define HSTRIDE 320                     // bytes per col in hbuf: 80 dw == 16 mod 32

__device__ __forceinline__ short f2b(float f) {
    __hip_bfloat16 b = __float2bfloat16(f); return *(short*)&b;
}
__device__ __forceinline__ float b2f(short s) {
    union { unsigned int u; float f; } v; v.u = ((unsigned int)(unsigned short)s) << 16; return v.f;
}
__device__ __forceinline__ float fexp2(float x) {
#if __has_builtin(__builtin_amdgcn_exp2f)
    return __builtin_amdgcn_exp2f(x);
#else
    return __expf(x * 0.6931471805599453f);
#endif
}
__device__ __forceinline__ float frcp(float x) { return __builtin_amdgcn_rcpf(x); }

// Spin until *f >= target. All 64 lanes poll the same LDS word (broadcast,
// conflict-free). Control dependency + lgkmcnt on the compare orders the
// subsequent h ds_reads after the flag observation; DS ops are in-order
// per wave.
__device__ __forceinline__ void spin_ge(volatile int* f, int target) {
    if (__builtin_expect(*f >= target, 1)) return;
    while (*f < target) __builtin_amdgcn_s_sleep(1);
}

__global__ __attribute__((amdgpu_flat_work_group_size(1024, 1024), amdgpu_waves_per_eu(4, 4)))
void lstm_i8(
    const int* __restrict__ x,
    const float* __restrict__ emb,
    const float* __restrict__ Wxg, const float* __restrict__ Whg, const float* __restrict__ bg,
    const float* __restrict__ Wxi, const float* __restrict__ Whi, const float* __restrict__ bi,
    const float* __restrict__ Wxf, const float* __restrict__ Whf, const float* __restrict__ bff,
    const float* __restrict__ Wxo, const float* __restrict__ Who, const float* __restrict__ bo,
    const float* __restrict__ Wp, const float* __restrict__ bp,
    float* __restrict__ out)
{
    const int tid = threadIdx.x, bid = blockIdx.x;
    const int c0 = bid * 2;                 // 2 batch columns per block
    const int w = tid >> 6, lane = tid & 63;
    const int jg = w >> 2;                  // k-slice group: owns h rows 64*jg..64*jg+63
    const int l = lane & 15, q = lane >> 4;
    const int col = l & 1;                  // this thread's column (8x dup)
    const int si  = (l >> 1) & 3;           // acc reg index
    const int dup = (l >> 3) & 1;           // pure duplicate bit
    const int rw  = 16 * w;                 // this wave's 16-row base
    const int row = rw + 4 * q + si;        // this thread's hidden row

    __shared__ __align__(16) unsigned int hbuf[2][2 * HSTRIDE / 4];  // h i8 [parity][col][k]
    __shared__ __align__(16) short hfin[2 * 264];                    // final h bf16 [col][k]
    __shared__ unsigned char xdig2[512 * 2];                         // [t][col]
    __shared__ __align__(16) float tblC[2 * 10 * 1024];              // [col][d][row][4g], bias folded
    __shared__ float scaleL[4 * 256];                                // per-gate per-row max|W|
    __shared__ int wcnt[4];                 // monotonic per-group write counters

    const float* WxT[4] = {Wxg, Wxi, Wxf, Wxo};
    const float* WhT[4] = {Whg, Whi, Whf, Who};
    const float* bT[4]  = {bg, bi, bff, bo};

    // ---- init: zero h buf0, stage digits, zero flags ----
    if (tid < 2 * HSTRIDE / 4) hbuf[0][tid] = 0u;
    if (tid < 1024)
        xdig2[tid] = (unsigned char)x[(c0 + (tid & 1)) * 512 + (tid >> 1)];
    if (tid < 4) wcnt[tid] = 0;

    // ---- x-path table per col, bias + gate-scale folded: tblC[c][d][r][g] ----
    // 5120 float4 entries = 2 cols x 10 digits x 256 rows (2560 per col)
    for (int i = tid; i < 5120; i += 1024) {
        int cc  = i / 2560;                   // 0 or 1
        int rem = i - cc * 2560;              // [0,2560)
        int d = rem >> 8, r = rem & 255;      // d in [0,10), consecutive lanes -> consecutive r
        float4v v;
        #pragma unroll
        for (int g = 0; g < 4; g++) {
            float s = 0.f;
            #pragma unroll
            for (int e = 0; e < 6; e++) s += WxT[g][r * 6 + e] * emb[d * 6 + e];
            v[g] = (s + bT[g][c0 + cc]) * (g == 0 ? K_TANH : K_SIG);
        }
        *(float4v*)&tblC[cc * 10240 + d * 1024 + r * 4] = v;
    }

    // ---- weight quantization: per-row scale, i8 A-frags in registers ----
    // A[m=lane&15 -> row rw+l][k = 64kt+16q+j], 16 i8 per lane per kt.
    // Chunk kk holds k-slice (jg+1+kk)&3 -> static register indexing in the
    // rotated consumption order (own slice LAST).
    int4v wb[4][4];
    #pragma unroll
    for (int g = 0; g < 4; g++) {
        const float* Wr = WhT[g] + (rw + l) * 256 + q * 16;
        float mx = 0.f;
        #pragma unroll
        for (int kt = 0; kt < 4; kt++)
            #pragma unroll
            for (int c4 = 0; c4 < 4; c4++) {
                float4v v = *(const float4v*)(Wr + kt * 64 + c4 * 4);
                #pragma unroll
                for (int jj = 0; jj < 4; jj++) mx = fmaxf(mx, fabsf(v[jj]));
            }
        mx = fmaxf(mx, __shfl_xor(mx, 16));
        mx = fmaxf(mx, __shfl_xor(mx, 32));
        mx = fmaxf(mx, 1e-20f);
        if (q == 0) scaleL[g * 256 + rw + l] = mx;
        float qs = 127.f / mx;
        #pragma unroll
        for (int kk = 0; kk < 4; kk++) {
            const int kt = (jg + 1 + kk) & 3;
            int4v fr;
            #pragma unroll
            for (int dw = 0; dw < 4; dw++) {
                float4v v = *(const float4v*)(Wr + kt * 64 + dw * 4);
                int word = 0;
                #pragma unroll
                for (int byt = 0; byt < 4; byt++) {
                    int z = (int)rintf(v[byt] * qs);
                    word |= (z & 255) << (8 * byt);
                }
                fr[dw] = word;
            }
            wb[g][kk] = fr;
        }
    }

    __syncthreads();   // scaleL/tblC/xdig2/hbuf[0]/wcnt visible

    // ---- loop-invariant: dequant scales (this thread's row) ----
    float dscl[4];
    #pragma unroll
    for (int g = 0; g < 4; g++) {
        float kk = (g == 0 ? K_TANH : K_SIG) * (1.f / 16129.f);   // 127^2
        dscl[g] = scaleL[g * 256 + row] * kk;
    }

    const bool bi1 = (si & 1) != 0;
    const bool bi2 = (si & 2) != 0;
    const float* tprow = tblC + col * 10240 + row * 4;   // + d*1024 at runtime
    const int hoff = col * HSTRIDE + row;                // this thread's h byte

    // loop-invariant chunk slice ids / LDS offsets / flag ptrs
    const int kts0 = (jg + 1) & 3, kts1 = (jg + 2) & 3, kts2 = (jg + 3) & 3, kts3 = jg;
    volatile int* fl0 = (volatile int*)&wcnt[kts0];
    volatile int* fl1 = (volatile int*)&wcnt[kts1];
    volatile int* fl2 = (volatile int*)&wcnt[kts2];
    volatile int* fl3 = (volatile int*)&wcnt[kts3];
    const int ho0 = kts0 * 64, ho1 = kts1 * 64, ho2 = kts2 * 64, ho3 = kts3 * 64;

    float cs = 0.f, hl = 0.f;

    for (int t = 0; t < 512; t++) {
        const int p = t & 1;
        const int tt = t << 2;              // flag target: 4 waves/group per step
        const char* hbase = (const char*)hbuf[p] + col * HSTRIDE + q * 16;

        int dg = xdig2[t * 2 + col];
        float4v tb = *(const float4v*)(tprow + dg * 1024);   // {tg,ti,tf,to} bias+kg folded

        // g0/g1: chunk-parity dual accumulators (shorter dep chain); g2/g3 single
        int4v a0e = {0,0,0,0}, a0o = {0,0,0,0};
        int4v a1e = {0,0,0,0}, a1o = {0,0,0,0};
        int4v a2  = {0,0,0,0}, a3  = {0,0,0,0};

        // ---- chunk 0: slice jg+1 ----
        if (t) spin_ge(fl0, tt);
        asm volatile("" ::: "memory");
        {
            int4v hf = *(const int4v*)(hbase + ho0);
            __builtin_amdgcn_s_setprio(1);
            a0e = MFMA_I8(wb[0][0], hf, a0e);
            a1e = MFMA_I8(wb[1][0], hf, a1e);
            a2  = MFMA_I8(wb[2][0], hf, a2);
            a3  = MFMA_I8(wb[3][0], hf, a3);
            __builtin_amdgcn_s_setprio(0);
        }
        // ---- chunk 1: slice jg+2 ----
        if (t) spin_ge(fl1, tt);
        asm volatile("" ::: "memory");
        {
            int4v hf = *(const int4v*)(hbase + ho1);
            __builtin_amdgcn_s_setprio(1);
            a0o = MFMA_I8(wb[0][1], hf, a0o);
            a1o = MFMA_I8(wb[1][1], hf, a1o);
            a2  = MFMA_I8(wb[2][1], hf, a2);
            a3  = MFMA_I8(wb[3][1], hf, a3);
            __builtin_amdgcn_s_setprio(0);
        }
        // ---- chunk 2: slice jg+3 ----
        if (t) spin_ge(fl2, tt);
        asm volatile("" ::: "memory");
        {
            int4v hf = *(const int4v*)(hbase + ho2);
            __builtin_amdgcn_s_setprio(1);
            a0e = MFMA_I8(wb[0][2], hf, a0e);
            a1e = MFMA_I8(wb[1][2], hf, a1e);
            a2  = MFMA_I8(wb[2][2], hf, a2);
            a3  = MFMA_I8(wb[3][2], hf, a3);
            __builtin_amdgcn_s_setprio(0);
        }
        // ---- chunk 3: own slice jg (self-gated: siblings only) ----
        if (t) spin_ge(fl3, tt);
        asm volatile("" ::: "memory");
        {
            int4v hf = *(const int4v*)(hbase + ho3);
            __builtin_amdgcn_s_setprio(1);
            a0o = MFMA_I8(wb[0][3], hf, a0o);
            a1o = MFMA_I8(wb[1][3], hf, a1o);
            a2  = MFMA_I8(wb[2][3], hf, a2);
            a3  = MFMA_I8(wb[3][3], hf, a3);
            __builtin_amdgcn_s_setprio(0);
        }

        int4v acc0, acc1;
        #pragma unroll
        for (int i = 0; i < 4; i++) { acc0[i] = a0e[i] + a0o[i]; acc1[i] = a1e[i] + a1o[i]; }

        // ---- elementwise: ONE element (row, col) per thread (dup lanes repeat) ----
        // select acc[si] via constant-index cndmask tree (3 per gate)
        int av0, av1, av2, av3;
        { int s0 = bi1 ? acc0[1] : acc0[0]; int s1 = bi1 ? acc0[3] : acc0[2]; av0 = bi2 ? s1 : s0; }
        { int s0 = bi1 ? acc1[1] : acc1[0]; int s1 = bi1 ? acc1[3] : acc1[2]; av1 = bi2 ? s1 : s0; }
        { int s0 = bi1 ? a2[1]   : a2[0];   int s1 = bi1 ? a2[3]   : a2[2];   av2 = bi2 ? s1 : s0; }
        { int s0 = bi1 ? a3[1]   : a3[0];   int s1 = bi1 ? a3[3]   : a3[2];   av3 = bi2 ? s1 : s0; }
        {
            float pg = fmaf((float)av0, dscl[0], tb[0]);
            float pi = fmaf((float)av1, dscl[1], tb[1]);
            float pf = fmaf((float)av2, dscl[2], tb[2]);
            float po = fmaf((float)av3, dscl[3], tb[3]);
            float Eg = fexp2(pg), Ei = fexp2(pi), Ef = fexp2(pf), Eo = fexp2(po);
            // c = [(1-Eg)(1+Ef) + cs(1+Eg)(1+Ei)] / [(1+Eg)(1+Ei)(1+Ef)]  (one rcp)
            float m1  = (1.f + Eg) * (1.f + Ei);
            float fp1 = 1.f + Ef;
            float num = fmaf(cs, m1, (1.f - Eg) * fp1);
            float c   = num * frcp(m1 * fp1);
            cs = c;
            float Ec = fexp2(K_TANH * c);
            float hh = (1.f - Ec) * frcp((1.f + Ec) * (1.f + Eo));   // tanh(c)*sig(o)
            hl = hh;
            // step-0 skew injection: serialize group writes once to seed the
            // pipeline stagger (group jg waits for group jg-1's 4 waves)
            if (t == 0 && jg != 0) spin_ge((volatile int*)&wcnt[jg - 1], 4);
            if (dup == 0)
                *((char*)hbuf[1 - p] + hoff) = (char)((int)rintf(hh * 127.f));
        }
        // publish: h bytes (DS in-order per wave) then release-inc own counter
        asm volatile("" ::: "memory");
        if (lane == 0)
            __hip_atomic_fetch_add(&wcnt[jg], 1, __ATOMIC_RELEASE, __HIP_MEMORY_SCOPE_WORKGROUP);
    }

    // ---- stage final h (exact f32->bf16) for projection ----
    if (dup == 0) hfin[col * 264 + row] = f2b(hl);
    __syncthreads();

    // ---- projection: out[c0+col][cls] = Wp[cls] . h_final + bp[cls] ----
    if (tid < 20) {
        int pc = tid / 10, cls = tid - pc * 10;
        const short* hcol = &hfin[pc * 264];
        const float* wrow = Wp + cls * 256;
        float s = 0.f;
        #pragma unroll 8
        for (int k = 0; k < 256; k++) s += b2f(hcol[k]) * wrow[k];
        out[(c0 + pc) * 10 + cls] = s + bp[cls];
    }
}

extern "C" void kernel_launch(void* const* d_in, const int* in_sizes, int n_in,
                              void* d_out, int out_size, void* d_ws, size_t ws_size,
                              hipStream_t stream) {
    const int*   x   = (const int*)d_in[0];
    const float* emb = (const float*)d_in[1];
    const float* Wxg = (const float*)d_in[2];
    const float* Whg = (const float*)d_in[3];
    const float* bg  = (const float*)d_in[4];
    const float* Wxi = (const float*)d_in[5];
    const float* Whi = (const float*)d_in[6];
    const float* bi  = (const float*)d_in[7];
    const float* Wxf = (const float*)d_in[8];
    const float* Whf = (const float*)d_in[9];
    const float* bff = (const float*)d_in[10];
    const float* Wxo = (const float*)d_in[11];
    const float* Who = (const float*)d_in[12];
    const float* bo  = (const float*)d_in[13];
    const float* Wp  = (const float*)d_in[14];
    const float* bp  = (const float*)d_in[15];

    hipLaunchKernelGGL(lstm_i8, dim3(128), dim3(1024), 0, stream,
                       x, emb, Wxg, Whg, bg, Wxi, Whi, bi, Wxf, Whf, bff,
                       Wxo, Who, bo, Wp, bp, (float*)d_out);
}

// Round 2
// 553.609 us; speedup vs baseline: 1.2609x; 1.2609x over previous
//
#include <hip/hip_runtime.h>
#include <hip/hip_bf16.h>

// LSTM B=256 T=512 H=256 E=6 V=10 C=10. fp32 in/out.
// ROUND 17: r15 structure (barrier/step) with the MFMA/VALU convoy broken by
// INTRA-WAVE INTERLEAVE. r15's per-active-CU MfmaUtil 44% + VALUBusy 56%
// ~= 100% sequential: program order was [16 MFMA][~90 VALU], so all 4
// waves/SIMD saturated the matrix pipe, then convoyed into the VALU phase
// (sum ~2460 cy/step). r16's flag-sync attempt regressed (+690 cy/step:
// spin-read latency serialized before each h ds_read + s_sleep quantization
// on a serial recurrence) -> reverted to __syncthreads.
// This round: issue k0..k2 MFMAs for all gates, then per-gate {final k3
// MFMA -> select/exp2 elementwise chunk} so each wave's VALU chunk overlaps
// its SIMD-siblings' MFMAs (separate pipes, 4 waves/SIMD). VALU fat trimmed
// on the serial path: single acc/gate (round-robin k order keeps 4 indep
// chains; -8 combine adds) and loop-invariant zero C-operand Z (-24 v_mov
// zero-inits/step).
// Structure otherwise r15: 128 blocks x 1024 thr (16 waves, 4/SIMD), 2
// cols/block, 8x n-dup, 1 elem/thread, INT8 MFMA (mfma_i32_16x16x64_i8),
// register-resident per-row-quantized weights, h @127 double-buffered LDS,
// bias folded into per-col x-table tblC (80 KB LDS), single-rcp c-update
// (5 exp2 + 2 rcp / elem), constant-index cndmask acc select (r9: never
// divergent-index a register array).

typedef __attribute__((ext_vector_type(4))) int   int4v;
typedef __attribute__((ext_vector_type(4))) float float4v;

#define MFMA_I8(a, b, c) __builtin_amdgcn_mfma_i32_16x16x64_i8(a, b, c, 0, 0, 0)

#define K_TANH (-2.8853900817779268f)   // exp2(K_TANH*x) = e^(-2x)
#define K_SIG  (-1.4426950408889634f)   // exp2(K_SIG*x)  = e^(-x)

#define HSTRIDE 320                     // bytes per col in hbuf: 80 dw == 16 mod 32

__device__ __forceinline__ short f2b(float f) {
    __hip_bfloat16 b = __float2bfloat16(f); return *(short*)&b;
}
__device__ __forceinline__ float b2f(short s) {
    union { unsigned int u; float f; } v; v.u = ((unsigned int)(unsigned short)s) << 16; return v.f;
}
__device__ __forceinline__ float fexp2(float x) {
#if __has_builtin(__builtin_amdgcn_exp2f)
    return __builtin_amdgcn_exp2f(x);
#else
    return __expf(x * 0.6931471805599453f);
#endif
}
__device__ __forceinline__ float frcp(float x) { return __builtin_amdgcn_rcpf(x); }

__global__ __attribute__((amdgpu_flat_work_group_size(1024, 1024), amdgpu_waves_per_eu(4, 4)))
void lstm_i8(
    const int* __restrict__ x,
    const float* __restrict__ emb,
    const float* __restrict__ Wxg, const float* __restrict__ Whg, const float* __restrict__ bg,
    const float* __restrict__ Wxi, const float* __restrict__ Whi, const float* __restrict__ bi,
    const float* __restrict__ Wxf, const float* __restrict__ Whf, const float* __restrict__ bff,
    const float* __restrict__ Wxo, const float* __restrict__ Who, const float* __restrict__ bo,
    const float* __restrict__ Wp, const float* __restrict__ bp,
    float* __restrict__ out)
{
    const int tid = threadIdx.x, bid = blockIdx.x;
    const int c0 = bid * 2;                 // 2 batch columns per block
    const int w = tid >> 6, lane = tid & 63;
    const int l = lane & 15, q = lane >> 4;
    const int col = l & 1;                  // this thread's column (8x dup)
    const int si  = (l >> 1) & 3;           // acc reg index
    const int dup = (l >> 3) & 1;           // pure duplicate bit
    const int rw  = 16 * w;                 // this wave's 16-row base
    const int row = rw + 4 * q + si;        // this thread's hidden row

    __shared__ __align__(16) unsigned int hbuf[2][2 * HSTRIDE / 4];  // h i8 [parity][col][k]
    __shared__ __align__(16) short hfin[2 * 264];                    // final h bf16 [col][k]
    __shared__ unsigned char xdig2[512 * 2];                         // [t][col]
    __shared__ __align__(16) float tblC[2 * 10 * 1024];              // [col][d][row][4g], bias folded
    __shared__ float scaleL[4 * 256];                                // per-gate per-row max|W|

    const float* WxT[4] = {Wxg, Wxi, Wxf, Wxo};
    const float* WhT[4] = {Whg, Whi, Whf, Who};
    const float* bT[4]  = {bg, bi, bff, bo};

    // ---- init: zero h buf0, stage digits ----
    if (tid < 2 * HSTRIDE / 4) hbuf[0][tid] = 0u;
    if (tid < 1024)
        xdig2[tid] = (unsigned char)x[(c0 + (tid & 1)) * 512 + (tid >> 1)];

    // ---- x-path table per col, bias + gate-scale folded: tblC[c][d][r][g] ----
    // 5120 float4 entries = 2 cols x 10 digits x 256 rows (2560 per col)
    for (int i = tid; i < 5120; i += 1024) {
        int cc  = i / 2560;                   // 0 or 1
        int rem = i - cc * 2560;              // [0,2560)
        int d = rem >> 8, r = rem & 255;      // d in [0,10), consecutive lanes -> consecutive r
        float4v v;
        #pragma unroll
        for (int g = 0; g < 4; g++) {
            float s = 0.f;
            #pragma unroll
            for (int e = 0; e < 6; e++) s += WxT[g][r * 6 + e] * emb[d * 6 + e];
            v[g] = (s + bT[g][c0 + cc]) * (g == 0 ? K_TANH : K_SIG);
        }
        *(float4v*)&tblC[cc * 10240 + d * 1024 + r * 4] = v;
    }

    // ---- weight quantization: per-row scale, i8 A-frags in registers ----
    // A[m=lane&15 -> row rw+l][k = 64kt+16q+j], 16 i8 per lane per kt
    int4v wa[4][4];
    #pragma unroll
    for (int g = 0; g < 4; g++) {
        const float* Wr = WhT[g] + (rw + l) * 256 + q * 16;
        float mx = 0.f;
        #pragma unroll
        for (int kt = 0; kt < 4; kt++)
            #pragma unroll
            for (int c4 = 0; c4 < 4; c4++) {
                float4v v = *(const float4v*)(Wr + kt * 64 + c4 * 4);
                #pragma unroll
                for (int j = 0; j < 4; j++) mx = fmaxf(mx, fabsf(v[j]));
            }
        mx = fmaxf(mx, __shfl_xor(mx, 16));
        mx = fmaxf(mx, __shfl_xor(mx, 32));
        mx = fmaxf(mx, 1e-20f);
        if (q == 0) scaleL[g * 256 + rw + l] = mx;
        float qs = 127.f / mx;
        #pragma unroll
        for (int kt = 0; kt < 4; kt++) {
            int4v f;
            #pragma unroll
            for (int dw = 0; dw < 4; dw++) {
                float4v v = *(const float4v*)(Wr + kt * 64 + dw * 4);
                int word = 0;
                #pragma unroll
                for (int byt = 0; byt < 4; byt++) {
                    int z = (int)rintf(v[byt] * qs);
                    word |= (z & 255) << (8 * byt);
                }
                f[dw] = word;
            }
            wa[g][kt] = f;
        }
    }

    __syncthreads();   // scaleL/tblC/xdig2/hbuf[0] visible

    // ---- loop-invariant: dequant scales (this thread's row) ----
    float dscl[4];
    #pragma unroll
    for (int g = 0; g < 4; g++) {
        float kk = (g == 0 ? K_TANH : K_SIG) * (1.f / 16129.f);   // 127^2
        dscl[g] = scaleL[g * 256 + row] * kk;
    }

    const bool bi1 = (si & 1) != 0;
    const bool bi2 = (si & 2) != 0;
    const float* tprow = tblC + col * 10240 + row * 4;   // + d*1024 at runtime
    const int hoff = col * HSTRIDE + row;                // this thread's h byte

    const int4v Z = {0, 0, 0, 0};          // loop-invariant zero C-operand

    float cs = 0.f, hl = 0.f;

    for (int t = 0; t < 512; t++) {
        const int p = t & 1;
        const char* hbase = (const char*)hbuf[p] + col * HSTRIDE + q * 16;   // dup lanes broadcast

        int dg = xdig2[t * 2 + col];
        float4v tb = *(const float4v*)(tprow + dg * 1024);   // {tg,ti,tf,to} bias+kg folded

        int4v hf0 = *(const int4v*)(hbase + 0 * 64);
        int4v hf1 = *(const int4v*)(hbase + 1 * 64);
        int4v hf2 = *(const int4v*)(hbase + 2 * 64);
        int4v hf3 = *(const int4v*)(hbase + 3 * 64);

        // k0..k2 for all gates: 4 independent chains, round-robin issue
        int4v ag = MFMA_I8(wa[0][0], hf0, Z);
        int4v ai = MFMA_I8(wa[1][0], hf0, Z);
        int4v af = MFMA_I8(wa[2][0], hf0, Z);
        int4v ao = MFMA_I8(wa[3][0], hf0, Z);
        ag = MFMA_I8(wa[0][1], hf1, ag);
        ai = MFMA_I8(wa[1][1], hf1, ai);
        af = MFMA_I8(wa[2][1], hf1, af);
        ao = MFMA_I8(wa[3][1], hf1, ao);
        ag = MFMA_I8(wa[0][2], hf2, ag);
        ai = MFMA_I8(wa[1][2], hf2, ai);
        af = MFMA_I8(wa[2][2], hf2, af);
        ao = MFMA_I8(wa[3][2], hf2, ao);

        // per-gate: final k3 MFMA, then that gate's elementwise chunk.
        // While this wave stalls on its select (MFMA result latency) and
        // burns VALU, SIMD-sibling waves keep the matrix pipe fed.
        ag = MFMA_I8(wa[0][3], hf3, ag);
        int avg_;
        { int s0 = bi1 ? ag[1] : ag[0]; int s1 = bi1 ? ag[3] : ag[2]; avg_ = bi2 ? s1 : s0; }
        float pg = fmaf((float)avg_, dscl[0], tb[0]);
        float Eg = fexp2(pg);

        ai = MFMA_I8(wa[1][3], hf3, ai);
        int avi_;
        { int s0 = bi1 ? ai[1] : ai[0]; int s1 = bi1 ? ai[3] : ai[2]; avi_ = bi2 ? s1 : s0; }
        float pi = fmaf((float)avi_, dscl[1], tb[1]);
        float Ei = fexp2(pi);
        float m1 = (1.f + Eg) * (1.f + Ei);

        af = MFMA_I8(wa[2][3], hf3, af);
        int avf_;
        { int s0 = bi1 ? af[1] : af[0]; int s1 = bi1 ? af[3] : af[2]; avf_ = bi2 ? s1 : s0; }
        float pf = fmaf((float)avf_, dscl[2], tb[2]);
        float Ef = fexp2(pf);
        // c = [(1-Eg)(1+Ef) + cs(1+Eg)(1+Ei)] / [(1+Eg)(1+Ei)(1+Ef)]  (one rcp)
        float fp1 = 1.f + Ef;
        float num = fmaf(cs, m1, (1.f - Eg) * fp1);
        float c   = num * frcp(m1 * fp1);
        cs = c;
        float Ec = fexp2(K_TANH * c);

        ao = MFMA_I8(wa[3][3], hf3, ao);
        int avo_;
        { int s0 = bi1 ? ao[1] : ao[0]; int s1 = bi1 ? ao[3] : ao[2]; avo_ = bi2 ? s1 : s0; }
        float po = fmaf((float)avo_, dscl[3], tb[3]);
        float Eo = fexp2(po);
        float hh = (1.f - Ec) * frcp((1.f + Ec) * (1.f + Eo));   // tanh(c)*sig(o)
        hl = hh;
        if (dup == 0)
            *((char*)hbuf[1 - p] + hoff) = (char)((int)rintf(hh * 127.f));

        __syncthreads();   // h_t (other buffer) fully written; h_{t-1} reads all done
    }

    // ---- stage final h (exact f32->bf16) for projection ----
    if (dup == 0) hfin[col * 264 + row] = f2b(hl);
    __syncthreads();

    // ---- projection: out[c0+col][cls] = Wp[cls] . h_final + bp[cls] ----
    if (tid < 20) {
        int pc = tid / 10, cls = tid - pc * 10;
        const short* hcol = &hfin[pc * 264];
        const float* wrow = Wp + cls * 256;
        float s = 0.f;
        #pragma unroll 8
        for (int k = 0; k < 256; k++) s += b2f(hcol[k]) * wrow[k];
        out[(c0 + pc) * 10 + cls] = s + bp[cls];
    }
}

extern "C" void kernel_launch(void* const* d_in, const int* in_sizes, int n_in,
                              void* d_out, int out_size, void* d_ws, size_t ws_size,
                              hipStream_t stream) {
    const int*   x   = (const int*)d_in[0];
    const float* emb = (const float*)d_in[1];
    const float* Wxg = (const float*)d_in[2];
    const float* Whg = (const float*)d_in[3];
    const float* bg  = (const float*)d_in[4];
    const float* Wxi = (const float*)d_in[5];
    const float* Whi = (const float*)d_in[6];
    const float* bi  = (const float*)d_in[7];
    const float* Wxf = (const float*)d_in[8];
    const float* Whf = (const float*)d_in[9];
    const float* bff = (const float*)d_in[10];
    const float* Wxo = (const float*)d_in[11];
    const float* Who = (const float*)d_in[12];
    const float* bo  = (const float*)d_in[13];
    const float* Wp  = (const float*)d_in[14];
    const float* bp  = (const float*)d_in[15];

    hipLaunchKernelGGL(lstm_i8, dim3(128), dim3(1024), 0, stream,
                       x, emb, Wxg, Whg, bg, Wxi, Whi, bi, Wxf, Whf, bff,
                       Wxo, Who, bo, Wp, bp, (float*)d_out);
}

// Round 3
// 544.170 us; speedup vs baseline: 1.2827x; 1.0173x over previous
//
#include <hip/hip_runtime.h>
#include <hip/hip_bf16.h>

// LSTM B=256 T=512 H=256 E=6 V=10 C=10. fp32 in/out.
// ROUND 18: 8-WAVE blocks (512 thr) to halve the per-CU LDS-pipe load.
// r15/r17 step arithmetic: MFMA busy ~1090 cy/CU/step (MfmaUtil 44.8%
// per-active-CU) + ~1000 cy of DS ops (16 waves x 4 ds_read_b128 for hf,
// 8x redundant, + tb/dig/h-writes) + tails ~= measured 2423 cy -> the step
// is DS-bound as much as MFMA-bound, and hf reads gate the MFMAs. r17's
// VALU interleave attacked the small term (~190 cy pure VALU) -> neutral.
// This round: 8 waves, each owns 32 rows (2 row-tiles, 32 MFMAs/step).
// B-frags (hf) are shared across gates AND row-tiles -> per-wave hf reads
// stay 4, per-CU DS ops halve (~-500 cy/step). Elementwise dup 2x -> 1x
// (every lane owns a distinct element, dup predication gone). Weights
// wa[2][4][4] = 128 VGPRs; waves_per_eu(2,2) -> 256-VGPR budget, ~210 peak.
// tb/digit for step t+1 prefetched during elementwise (independent of h).
// Kept from r17: barrier/step double-buffered h, Z C-operand, round-robin
// chains, per-gate elementwise chunks after that gate's last MFMA,
// single-rcp c-update (5 exp2 + 2 rcp / elem), constant-index cndmask
// select (never divergent-index a register array).

typedef __attribute__((ext_vector_type(4))) int   int4v;
typedef __attribute__((ext_vector_type(4))) float float4v;

#define MFMA_I8(a, b, c) __builtin_amdgcn_mfma_i32_16x16x64_i8(a, b, c, 0, 0, 0)

#define K_TANH (-2.8853900817779268f)   // exp2(K_TANH*x) = e^(-2x)
#define K_SIG  (-1.4426950408889634f)   // exp2(K_SIG*x)  = e^(-x)

#define HSTRIDE 320                     // bytes per col in hbuf: 80 dw == 16 mod 32

__device__ __forceinline__ short f2b(float f) {
    __hip_bfloat16 b = __float2bfloat16(f); return *(short*)&b;
}
__device__ __forceinline__ float b2f(short s) {
    union { unsigned int u; float f; } v; v.u = ((unsigned int)(unsigned short)s) << 16; return v.f;
}
__device__ __forceinline__ float fexp2(float x) {
#if __has_builtin(__builtin_amdgcn_exp2f)
    return __builtin_amdgcn_exp2f(x);
#else
    return __expf(x * 0.6931471805599453f);
#endif
}
__device__ __forceinline__ float frcp(float x) { return __builtin_amdgcn_rcpf(x); }

__global__ __attribute__((amdgpu_flat_work_group_size(512, 512), amdgpu_waves_per_eu(2, 2)))
void lstm_i8(
    const int* __restrict__ x,
    const float* __restrict__ emb,
    const float* __restrict__ Wxg, const float* __restrict__ Whg, const float* __restrict__ bg,
    const float* __restrict__ Wxi, const float* __restrict__ Whi, const float* __restrict__ bi,
    const float* __restrict__ Wxf, const float* __restrict__ Whf, const float* __restrict__ bff,
    const float* __restrict__ Wxo, const float* __restrict__ Who, const float* __restrict__ bo,
    const float* __restrict__ Wp, const float* __restrict__ bp,
    float* __restrict__ out)
{
    const int tid = threadIdx.x, bid = blockIdx.x;
    const int c0 = bid * 2;                 // 2 batch columns per block
    const int w = tid >> 6, lane = tid & 63;
    const int l = lane & 15, q = lane >> 4;
    const int col = lane & 1;               // this thread's column (B n-parity)
    const int rtb = (lane >> 1) & 1;        // row-tile select bit
    const int si  = (lane >> 2) & 3;        // acc reg index
    const int rwb = 32 * w;                 // this wave's 32-row base
    const int row = rwb + 16 * rtb + 4 * q + si;   // this thread's hidden row

    __shared__ __align__(16) unsigned int hbuf[2][2 * HSTRIDE / 4];  // h i8 [parity][col][k]
    __shared__ __align__(16) short hfin[2 * 264];                    // final h bf16 [col][k]
    __shared__ unsigned char xdig2[512 * 2];                         // [t][col]
    __shared__ __align__(16) float tblC[2 * 10 * 1024];              // [col][d][row][4g], bias folded
    __shared__ float scaleL[4 * 256];                                // per-gate per-row max|W|

    const float* WxT[4] = {Wxg, Wxi, Wxf, Wxo};
    const float* WhT[4] = {Whg, Whi, Whf, Who};
    const float* bT[4]  = {bg, bi, bff, bo};

    // ---- init: zero h buf0, stage digits ----
    if (tid < 2 * HSTRIDE / 4) hbuf[0][tid] = 0u;
    for (int i = tid; i < 1024; i += 512)
        xdig2[i] = (unsigned char)x[(c0 + (i & 1)) * 512 + (i >> 1)];

    // ---- x-path table per col, bias + gate-scale folded: tblC[c][d][r][g] ----
    // 5120 float4 entries = 2 cols x 10 digits x 256 rows (2560 per col)
    for (int i = tid; i < 5120; i += 512) {
        int cc  = i / 2560;                   // 0 or 1
        int rem = i - cc * 2560;              // [0,2560)
        int d = rem >> 8, r = rem & 255;      // d in [0,10), consecutive lanes -> consecutive r
        float4v v;
        #pragma unroll
        for (int g = 0; g < 4; g++) {
            float s = 0.f;
            #pragma unroll
            for (int e = 0; e < 6; e++) s += WxT[g][r * 6 + e] * emb[d * 6 + e];
            v[g] = (s + bT[g][c0 + cc]) * (g == 0 ? K_TANH : K_SIG);
        }
        *(float4v*)&tblC[cc * 10240 + d * 1024 + r * 4] = v;
    }

    // ---- weight quantization: per-row scale, i8 A-frags in registers ----
    // Per row-tile rt (rows rwb+16rt .. +15): A[m=l -> row rwb+16rt+l]
    // [k = 64kt+16q+j], 16 i8 per lane per kt. wa[rt][g][kt] = 128 VGPRs.
    int4v wa[2][4][4];
    #pragma unroll
    for (int rt = 0; rt < 2; rt++) {
        #pragma unroll
        for (int g = 0; g < 4; g++) {
            const float* Wr = WhT[g] + (rwb + rt * 16 + l) * 256 + q * 16;
            float mx = 0.f;
            #pragma unroll
            for (int kt = 0; kt < 4; kt++)
                #pragma unroll
                for (int c4 = 0; c4 < 4; c4++) {
                    float4v v = *(const float4v*)(Wr + kt * 64 + c4 * 4);
                    #pragma unroll
                    for (int j = 0; j < 4; j++) mx = fmaxf(mx, fabsf(v[j]));
                }
            mx = fmaxf(mx, __shfl_xor(mx, 16));
            mx = fmaxf(mx, __shfl_xor(mx, 32));
            mx = fmaxf(mx, 1e-20f);
            if (q == 0) scaleL[g * 256 + rwb + rt * 16 + l] = mx;
            float qs = 127.f / mx;
            #pragma unroll
            for (int kt = 0; kt < 4; kt++) {
                int4v f;
                #pragma unroll
                for (int dw = 0; dw < 4; dw++) {
                    float4v v = *(const float4v*)(Wr + kt * 64 + dw * 4);
                    int word = 0;
                    #pragma unroll
                    for (int byt = 0; byt < 4; byt++) {
                        int z = (int)rintf(v[byt] * qs);
                        word |= (z & 255) << (8 * byt);
                    }
                    f[dw] = word;
                }
                wa[rt][g][kt] = f;
            }
        }
    }

    __syncthreads();   // scaleL/tblC/xdig2/hbuf[0] visible

    // ---- loop-invariant: dequant scales (this thread's row) ----
    float dscl[4];
    #pragma unroll
    for (int g = 0; g < 4; g++) {
        float kk = (g == 0 ? K_TANH : K_SIG) * (1.f / 16129.f);   // 127^2
        dscl[g] = scaleL[g * 256 + row] * kk;
    }

    const bool bi1 = (si & 1) != 0;
    const bool bi2 = (si & 2) != 0;
    const bool brt = rtb != 0;
    const float* tprow = tblC + col * 10240 + row * 4;   // + d*1024 at runtime
    const int hoff = col * HSTRIDE + row;                // this thread's h byte

    const int4v Z = {0, 0, 0, 0};          // loop-invariant zero C-operand

    float cs = 0.f, hl = 0.f;

    // prefetch tb for t=0
    float4v tb;
    { int dg = xdig2[0 * 2 + col]; tb = *(const float4v*)(tprow + dg * 1024); }

    for (int t = 0; t < 512; t++) {
        const int p = t & 1;
        const char* hbase = (const char*)hbuf[p] + col * HSTRIDE + q * 16;

        int4v hf0 = *(const int4v*)(hbase + 0 * 64);
        int4v hf1 = *(const int4v*)(hbase + 1 * 64);
        int4v hf2 = *(const int4v*)(hbase + 2 * 64);
        int4v hf3 = *(const int4v*)(hbase + 3 * 64);

        // k0..k2 for all 8 chains (2 row-tiles x 4 gates), round-robin issue
        int4v ag0 = MFMA_I8(wa[0][0][0], hf0, Z);
        int4v ag1 = MFMA_I8(wa[1][0][0], hf0, Z);
        int4v ai0 = MFMA_I8(wa[0][1][0], hf0, Z);
        int4v ai1 = MFMA_I8(wa[1][1][0], hf0, Z);
        int4v af0 = MFMA_I8(wa[0][2][0], hf0, Z);
        int4v af1 = MFMA_I8(wa[1][2][0], hf0, Z);
        int4v ao0 = MFMA_I8(wa[0][3][0], hf0, Z);
        int4v ao1 = MFMA_I8(wa[1][3][0], hf0, Z);
        ag0 = MFMA_I8(wa[0][0][1], hf1, ag0);
        ag1 = MFMA_I8(wa[1][0][1], hf1, ag1);
        ai0 = MFMA_I8(wa[0][1][1], hf1, ai0);
        ai1 = MFMA_I8(wa[1][1][1], hf1, ai1);
        af0 = MFMA_I8(wa[0][2][1], hf1, af0);
        af1 = MFMA_I8(wa[1][2][1], hf1, af1);
        ao0 = MFMA_I8(wa[0][3][1], hf1, ao0);
        ao1 = MFMA_I8(wa[1][3][1], hf1, ao1);
        ag0 = MFMA_I8(wa[0][0][2], hf2, ag0);
        ag1 = MFMA_I8(wa[1][0][2], hf2, ag1);
        ai0 = MFMA_I8(wa[0][1][2], hf2, ai0);
        ai1 = MFMA_I8(wa[1][1][2], hf2, ai1);
        af0 = MFMA_I8(wa[0][2][2], hf2, af0);
        af1 = MFMA_I8(wa[1][2][2], hf2, af1);
        ao0 = MFMA_I8(wa[0][3][2], hf2, ao0);
        ao1 = MFMA_I8(wa[1][3][2], hf2, ao1);

        // prefetch tb for t+1 (independent of h; overlaps MFMA/elementwise)
        float4v tbn;
        { int dgn = xdig2[((t + 1) & 511) * 2 + col]; tbn = *(const float4v*)(tprow + dgn * 1024); }

        // per-gate: final k3 MFMA pair, then that gate's elementwise chunk
        ag0 = MFMA_I8(wa[0][0][3], hf3, ag0);
        ag1 = MFMA_I8(wa[1][0][3], hf3, ag1);
        int avg_;
        { int t0 = bi1 ? ag0[1] : ag0[0]; int t1 = bi1 ? ag0[3] : ag0[2]; int s0 = bi2 ? t1 : t0;
          int u0 = bi1 ? ag1[1] : ag1[0]; int u1 = bi1 ? ag1[3] : ag1[2]; int s1 = bi2 ? u1 : u0;
          avg_ = brt ? s1 : s0; }
        float pg = fmaf((float)avg_, dscl[0], tb[0]);
        float Eg = fexp2(pg);

        ai0 = MFMA_I8(wa[0][1][3], hf3, ai0);
        ai1 = MFMA_I8(wa[1][1][3], hf3, ai1);
        int avi_;
        { int t0 = bi1 ? ai0[1] : ai0[0]; int t1 = bi1 ? ai0[3] : ai0[2]; int s0 = bi2 ? t1 : t0;
          int u0 = bi1 ? ai1[1] : ai1[0]; int u1 = bi1 ? ai1[3] : ai1[2]; int s1 = bi2 ? u1 : u0;
          avi_ = brt ? s1 : s0; }
        float pi = fmaf((float)avi_, dscl[1], tb[1]);
        float Ei = fexp2(pi);
        float m1 = (1.f + Eg) * (1.f + Ei);

        af0 = MFMA_I8(wa[0][2][3], hf3, af0);
        af1 = MFMA_I8(wa[1][2][3], hf3, af1);
        int avf_;
        { int t0 = bi1 ? af0[1] : af0[0]; int t1 = bi1 ? af0[3] : af0[2]; int s0 = bi2 ? t1 : t0;
          int u0 = bi1 ? af1[1] : af1[0]; int u1 = bi1 ? af1[3] : af1[2]; int s1 = bi2 ? u1 : u0;
          avf_ = brt ? s1 : s0; }
        float pf = fmaf((float)avf_, dscl[2], tb[2]);
        float Ef = fexp2(pf);
        // c = [(1-Eg)(1+Ef) + cs(1+Eg)(1+Ei)] / [(1+Eg)(1+Ei)(1+Ef)]  (one rcp)
        float fp1 = 1.f + Ef;
        float num = fmaf(cs, m1, (1.f - Eg) * fp1);
        float c   = num * frcp(m1 * fp1);
        cs = c;
        float Ec = fexp2(K_TANH * c);

        ao0 = MFMA_I8(wa[0][3][3], hf3, ao0);
        ao1 = MFMA_I8(wa[1][3][3], hf3, ao1);
        int avo_;
        { int t0 = bi1 ? ao0[1] : ao0[0]; int t1 = bi1 ? ao0[3] : ao0[2]; int s0 = bi2 ? t1 : t0;
          int u0 = bi1 ? ao1[1] : ao1[0]; int u1 = bi1 ? ao1[3] : ao1[2]; int s1 = bi2 ? u1 : u0;
          avo_ = brt ? s1 : s0; }
        float po = fmaf((float)avo_, dscl[3], tb[3]);
        float Eo = fexp2(po);
        float hh = (1.f - Ec) * frcp((1.f + Ec) * (1.f + Eo));   // tanh(c)*sig(o)
        hl = hh;
        *((char*)hbuf[1 - p] + hoff) = (char)((int)rintf(hh * 127.f));

        tb = tbn;
        __syncthreads();   // h_t (other buffer) fully written; h_{t-1} reads all done
    }

    // ---- stage final h (exact f32->bf16) for projection ----
    hfin[col * 264 + row] = f2b(hl);
    __syncthreads();

    // ---- projection: out[c0+col][cls] = Wp[cls] . h_final + bp[cls] ----
    if (tid < 20) {
        int pc = tid / 10, cls = tid - pc * 10;
        const short* hcol = &hfin[pc * 264];
        const float* wrow = Wp + cls * 256;
        float s = 0.f;
        #pragma unroll 8
        for (int k = 0; k < 256; k++) s += b2f(hcol[k]) * wrow[k];
        out[(c0 + pc) * 10 + cls] = s + bp[cls];
    }
}

extern "C" void kernel_launch(void* const* d_in, const int* in_sizes, int n_in,
                              void* d_out, int out_size, void* d_ws, size_t ws_size,
                              hipStream_t stream) {
    const int*   x   = (const int*)d_in[0];
    const float* emb = (const float*)d_in[1];
    const float* Wxg = (const float*)d_in[2];
    const float* Whg = (const float*)d_in[3];
    const float* bg  = (const float*)d_in[4];
    const float* Wxi = (const float*)d_in[5];
    const float* Whi = (const float*)d_in[6];
    const float* bi  = (const float*)d_in[7];
    const float* Wxf = (const float*)d_in[8];
    const float* Whf = (const float*)d_in[9];
    const float* bff = (const float*)d_in[10];
    const float* Wxo = (const float*)d_in[11];
    const float* Who = (const float*)d_in[12];
    const float* bo  = (const float*)d_in[13];
    const float* Wp  = (const float*)d_in[14];
    const float* bp  = (const float*)d_in[15];

    hipLaunchKernelGGL(lstm_i8, dim3(128), dim3(512), 0, stream,
                       x, emb, Wxg, Whg, bg, Wxi, Whi, bi, Wxf, Whf, bff,
                       Wxo, Who, bo, Wp, bp, (float*)d_out);
}